// Round 6
// baseline (499.450 us; speedup 1.0000x reference)
//
#include <hip/hip_runtime.h>
#include <hip/hip_fp16.h>

#define HID 64
#define SCAN_BLOCK 256
#define SCAN_ITEMS 16
#define SCAN_TILE (SCAN_BLOCK * SCAN_ITEMS)   // 4096 elements per block

__device__ __forceinline__ unsigned short f32_to_bf16_bits(float f) {
    unsigned u = __float_as_uint(f);
    unsigned r = (u + 0x7fff + ((u >> 16) & 1)) >> 16;   // round-to-nearest-even
    return (unsigned short)r;
}
__device__ __forceinline__ float bf16_bits_to_f32(unsigned short b) {
    return __uint_as_float((unsigned)b << 16);
}

// x[n][h] = emb[z[n]][h]; also writes bf16 shadow copy for gather's neighbor reads
__global__ void embed_kernel(const int* __restrict__ z, const float* __restrict__ emb,
                             float* __restrict__ x, unsigned short* __restrict__ x16, int n) {
    int t = blockIdx.x * blockDim.x + threadIdx.x;
    if (t >= n * HID) return;
    int node = t >> 6, h = t & 63;
    float v = emb[z[node] * HID + h];
    x[t] = v;
    x16[t] = f32_to_bf16_bits(v);
}

// deg[row[e]]++  (1 edge/thread — max parallelism; R4 showed batching hurts here)
__global__ void hist_kernel(const int* __restrict__ row, int* __restrict__ deg, int e) {
    int t = blockIdx.x * blockDim.x + threadIdx.x;
    if (t < e) atomicAdd(&deg[row[t]], 1);
}

// ---- 3-phase exclusive scan of deg[0..n1) into offs[0..n1) ----
__global__ void scanA_kernel(const int* __restrict__ deg, int* __restrict__ offs,
                             int* __restrict__ bsums, int n1) {
    __shared__ int wsum[SCAN_BLOCK / 64];
    int tid  = threadIdx.x;
    int lane = tid & 63, w = tid >> 6;
    int tbase = blockIdx.x * SCAN_TILE + tid * SCAN_ITEMS;

    int vals[SCAN_ITEMS];
    int s = 0;
#pragma unroll
    for (int i = 0; i < SCAN_ITEMS; ++i) {
        int idx = tbase + i;
        vals[i] = (idx < n1) ? deg[idx] : 0;
        s += vals[i];
    }
    int sc = s;
#pragma unroll
    for (int d = 1; d < 64; d <<= 1) {
        int t2 = __shfl_up(sc, d);
        if (lane >= d) sc += t2;
    }
    if (lane == 63) wsum[w] = sc;
    __syncthreads();
    int woff = 0;
    for (int i = 0; i < w; ++i) woff += wsum[i];
    int texcl = woff + sc - s;
    if (tid == 0) {
        int tot = 0;
        for (int i = 0; i < SCAN_BLOCK / 64; ++i) tot += wsum[i];
        bsums[blockIdx.x] = tot;
    }
    int run = 0;
#pragma unroll
    for (int i = 0; i < SCAN_ITEMS; ++i) {
        int idx = tbase + i;
        if (idx < n1) offs[idx] = texcl + run;
        run += vals[i];
    }
}

__global__ void scanB_kernel(int* __restrict__ bsums, int nb) {
    __shared__ int wsum[SCAN_BLOCK / 64];
    __shared__ int chunk_tot;
    int tid = threadIdx.x, lane = tid & 63, w = tid >> 6;
    int carry = 0;
    for (int base = 0; base < nb; base += SCAN_BLOCK) {
        int idx = base + tid;
        int v = (idx < nb) ? bsums[idx] : 0;
        int sc = v;
#pragma unroll
        for (int d = 1; d < 64; d <<= 1) {
            int t2 = __shfl_up(sc, d);
            if (lane >= d) sc += t2;
        }
        if (lane == 63) wsum[w] = sc;
        __syncthreads();
        int woff = 0;
        for (int i = 0; i < w; ++i) woff += wsum[i];
        if (idx < nb) bsums[idx] = carry + woff + sc - v;
        if (tid == SCAN_BLOCK - 1) chunk_tot = woff + sc;
        __syncthreads();
        carry += chunk_tot;
        __syncthreads();
    }
}

__global__ void scanC_kernel(int* __restrict__ offs, const int* __restrict__ bsums, int n1) {
    int t = blockIdx.x * blockDim.x + threadIdx.x;
    if (t < n1) offs[t] += bsums[t / SCAN_TILE];
}

// CSR fill + fused rbf, packed 4-byte record: (col << 15) | fp16(rbf) sans sign.
// col < 2^17 (N=100k), rbf in (0,1] so fp16 sign bit is always 0.
// NOTE (R5): bound by ~1M random dirty-line RMWs (~1.4 TB/s effective) — record
// size does NOT matter; a future fix needs destination binning, not packing.
__global__ void fill_kernel(const int* __restrict__ row, const int* __restrict__ col,
                            const float* __restrict__ pos, int* __restrict__ cursor,
                            unsigned* __restrict__ ecr, int e) {
    int t = blockIdx.x * blockDim.x + threadIdx.x;
    if (t >= e) return;
    int r = row[t], c = col[t];
    float dx = pos[3 * r]     - pos[3 * c];
    float dy = pos[3 * r + 1] - pos[3 * c + 1];
    float dz = pos[3 * r + 2] - pos[3 * c + 2];
    float rbf = expf(-sqrtf(dx * dx + dy * dy + dz * dz));
    unsigned short hb = __half_as_ushort(__float2half(rbf));   // sign bit = 0
    int p = atomicAdd(&cursor[r], 1);
    ecr[p] = ((unsigned)c << 15) | (unsigned)hb;
}

// FUSED layer: y[n] = x[n] + sum_{(n,c)} bf16(x[c])*rbf ; out[n] = relu(y W^T + b)
// One wave per node, lane = h. After the gather loop the wave holds the FULL
// y-row across its 64 lanes, so the 64x64 linear is done in-wave:
//   out_h = b_h + sum_k shfl(y,k) * W[h][k]
// W lives in LDS with pitch 65: bank((h*65+k)%32) = (h+k)%32 -> 2 lanes/bank,
// conflict-free (m136). Epilogue is ~500 cyc/node of VALU/LDS that hides in
// the gather's memory-wait bubbles; saves a 51 MB/layer global round trip and
// the entire (latency-bound) linear dispatch. Numerics identical to split.
__global__ void layer_kernel(const float* __restrict__ xres, const unsigned short* __restrict__ x16,
                             const int* __restrict__ offs, const unsigned* __restrict__ ecr,
                             const float* __restrict__ W, const float* __restrict__ b,
                             float* __restrict__ outres, unsigned short* __restrict__ out16, int n) {
    __shared__ float wlds[HID * 65];
    int tid = threadIdx.x;
    for (int i = tid; i < HID * HID; i += 256)
        wlds[(i >> 6) * 65 + (i & 63)] = W[i];
    __syncthreads();

    int lane = tid & 63;
    float bias = b[lane];
    int wid = (blockIdx.x * blockDim.x + tid) >> 6;
    int nw = (gridDim.x * blockDim.x) >> 6;
    for (int node = wid; node < n; node += nw) {
        int nu = __builtin_amdgcn_readfirstlane(node);
        int beg = offs[nu], end = offs[nu + 1];
        float acc = xres[nu * HID + lane];               // residual in fp32
        for (int cbeg = beg; cbeg < end; cbeg += 64) {
            int m = end - cbeg; if (m > 64) m = 64;
            unsigned wrd = (lane < m) ? ecr[cbeg + lane] : 0u;
            int j = 0;
            for (; j + 8 <= m; j += 8) {
                unsigned w0 = __shfl(wrd, j);
                unsigned w1 = __shfl(wrd, j + 1);
                unsigned w2 = __shfl(wrd, j + 2);
                unsigned w3 = __shfl(wrd, j + 3);
                unsigned w4 = __shfl(wrd, j + 4);
                unsigned w5 = __shfl(wrd, j + 5);
                unsigned w6 = __shfl(wrd, j + 6);
                unsigned w7 = __shfl(wrd, j + 7);
                float v0 = bf16_bits_to_f32(x16[(w0 >> 15) * HID + lane]);
                float v1 = bf16_bits_to_f32(x16[(w1 >> 15) * HID + lane]);
                float v2 = bf16_bits_to_f32(x16[(w2 >> 15) * HID + lane]);
                float v3 = bf16_bits_to_f32(x16[(w3 >> 15) * HID + lane]);
                float v4 = bf16_bits_to_f32(x16[(w4 >> 15) * HID + lane]);
                float v5 = bf16_bits_to_f32(x16[(w5 >> 15) * HID + lane]);
                float v6 = bf16_bits_to_f32(x16[(w6 >> 15) * HID + lane]);
                float v7 = bf16_bits_to_f32(x16[(w7 >> 15) * HID + lane]);
                acc = fmaf(v0, __half2float(__ushort_as_half((unsigned short)(w0 & 0x7fff))), acc);
                acc = fmaf(v1, __half2float(__ushort_as_half((unsigned short)(w1 & 0x7fff))), acc);
                acc = fmaf(v2, __half2float(__ushort_as_half((unsigned short)(w2 & 0x7fff))), acc);
                acc = fmaf(v3, __half2float(__ushort_as_half((unsigned short)(w3 & 0x7fff))), acc);
                acc = fmaf(v4, __half2float(__ushort_as_half((unsigned short)(w4 & 0x7fff))), acc);
                acc = fmaf(v5, __half2float(__ushort_as_half((unsigned short)(w5 & 0x7fff))), acc);
                acc = fmaf(v6, __half2float(__ushort_as_half((unsigned short)(w6 & 0x7fff))), acc);
                acc = fmaf(v7, __half2float(__ushort_as_half((unsigned short)(w7 & 0x7fff))), acc);
            }
            for (; j < m; ++j) {
                unsigned w0 = __shfl(wrd, j);
                float v0 = bf16_bits_to_f32(x16[(w0 >> 15) * HID + lane]);
                acc = fmaf(v0, __half2float(__ushort_as_half((unsigned short)(w0 & 0x7fff))), acc);
            }
        }
        // in-wave 64x64 linear: lane h computes out_h
        float o = bias;
#pragma unroll
        for (int k = 0; k < HID; ++k) {
            float yk = __shfl(acc, k);                   // broadcast y[k]
            o = fmaf(yk, wlds[lane * 65 + k], o);
        }
        o = fmaxf(o, 0.0f);
        outres[nu * HID + lane] = o;
        if (out16) out16[nu * HID + lane] = f32_to_bf16_bits(o);
    }
}

extern "C" void kernel_launch(void* const* d_in, const int* in_sizes, int n_in,
                              void* d_out, int out_size, void* d_ws, size_t ws_size,
                              hipStream_t stream) {
    const int*   z    = (const int*)d_in[0];
    const float* pos  = (const float*)d_in[1];
    const int*   eidx = (const int*)d_in[2];
    const float* emb  = (const float*)d_in[3];
    const float* Ws   = (const float*)d_in[4];
    const float* bs   = (const float*)d_in[5];
    int n = in_sizes[0];
    int e = in_sizes[2] / 2;
    int nlayers = in_sizes[4] / (HID * HID);
    const int* row = eidx;
    const int* col = eidx + e;
    float* out = (float*)d_out;

    char* ws = (char*)d_ws;
    float*          A      = (float*)ws;                                       // n*64 f32 (25.6 MB)
    unsigned short* A16a   = (unsigned short*)(ws + (size_t)n * HID * 4);      // n*64 bf16 (12.8 MB)
    unsigned short* A16b   = A16a + (size_t)n * HID;                           // n*64 bf16 (12.8 MB)
    unsigned*       ecr    = (unsigned*)((char*)A16b + (size_t)n * HID * 2);   // e u32 (4 MB)
    int*            deg    = (int*)((char*)ecr + (size_t)e * 4);
    int*            offs   = deg + (n + 1);
    int*            cursor = offs + (n + 1);
    int*            bsums  = cursor + (n + 1);

    int n1 = n + 1;
    int nb = (n1 + SCAN_TILE - 1) / SCAN_TILE;

    hipMemsetAsync(deg, 0, n1 * sizeof(int), stream);
    embed_kernel<<<(n * HID + 255) / 256, 256, 0, stream>>>(z, emb, A, A16a, n);
    hist_kernel<<<(e + 255) / 256, 256, 0, stream>>>(row, deg, e);
    scanA_kernel<<<nb, SCAN_BLOCK, 0, stream>>>(deg, offs, bsums, n1);
    scanB_kernel<<<1, SCAN_BLOCK, 0, stream>>>(bsums, nb);
    scanC_kernel<<<(n1 + 255) / 256, 256, 0, stream>>>(offs, bsums, n1);
    hipMemcpyAsync(cursor, offs, n * sizeof(int), hipMemcpyDeviceToDevice, stream);
    fill_kernel<<<(e + 255) / 256, 256, 0, stream>>>(row, col, pos, cursor, ecr, e);

    // fp32 ping-pong: A <-> out (even layers write out, odd write A; nlayers=3
    // so the final layer lands in out). bf16 ping-pong: A16a <-> A16b.
    for (int l = 0; l < nlayers; ++l) {
        bool last = (l == nlayers - 1);
        const float*          src32 = (l % 2 == 0) ? A : out;
        float*                dst32 = (l % 2 == 0) ? out : A;
        const unsigned short* src16 = (l % 2 == 0) ? A16a : A16b;
        unsigned short*       dst16 = last ? nullptr : ((l % 2 == 0) ? A16b : A16a);
        layer_kernel<<<2048, 256, 0, stream>>>(src32, src16, offs, ecr,
                                               Ws + (size_t)l * HID * HID,
                                               bs + (size_t)l * HID,
                                               dst32, dst16, n);
    }
    if (nlayers % 2 == 0)   // generality: even layer count ends in A
        hipMemcpyAsync(out, A, (size_t)n * HID * 4, hipMemcpyDeviceToDevice, stream);
}

// Round 7
// 387.938 us; speedup vs baseline: 1.2874x; 1.2874x over previous
//
#include <hip/hip_runtime.h>
#include <hip/hip_fp16.h>

#define HID 64
#define SCAN_BLOCK 256
#define SCAN_ITEMS 16
#define SCAN_TILE (SCAN_BLOCK * SCAN_ITEMS)   // 4096 elements per block

__device__ __forceinline__ unsigned short f32_to_bf16_bits(float f) {
    unsigned u = __float_as_uint(f);
    unsigned r = (u + 0x7fff + ((u >> 16) & 1)) >> 16;   // round-to-nearest-even
    return (unsigned short)r;
}
__device__ __forceinline__ float bf16_bits_to_f32(unsigned short b) {
    return __uint_as_float((unsigned)b << 16);
}
__device__ __forceinline__ float rbf_of(unsigned w) {
    return __half2float(__ushort_as_half((unsigned short)(w & 0x7fff)));
}

// x[n][h] = emb[z[n]][h]; also writes bf16 shadow copy for gather's neighbor reads
__global__ void embed_kernel(const int* __restrict__ z, const float* __restrict__ emb,
                             float* __restrict__ x, unsigned short* __restrict__ x16, int n) {
    int t = blockIdx.x * blockDim.x + threadIdx.x;
    if (t >= n * HID) return;
    int node = t >> 6, h = t & 63;
    float v = emb[z[node] * HID + h];
    x[t] = v;
    x16[t] = f32_to_bf16_bits(v);
}

// deg[row[e]]++  (1 edge/thread — R4 showed batching kills occupancy here)
__global__ void hist_kernel(const int* __restrict__ row, int* __restrict__ deg, int e) {
    int t = blockIdx.x * blockDim.x + threadIdx.x;
    if (t < e) atomicAdd(&deg[row[t]], 1);
}

// ---- 3-phase exclusive scan of deg[0..n1) into offs[0..n1) ----
__global__ void scanA_kernel(const int* __restrict__ deg, int* __restrict__ offs,
                             int* __restrict__ bsums, int n1) {
    __shared__ int wsum[SCAN_BLOCK / 64];
    int tid  = threadIdx.x;
    int lane = tid & 63, w = tid >> 6;
    int tbase = blockIdx.x * SCAN_TILE + tid * SCAN_ITEMS;

    int vals[SCAN_ITEMS];
    int s = 0;
#pragma unroll
    for (int i = 0; i < SCAN_ITEMS; ++i) {
        int idx = tbase + i;
        vals[i] = (idx < n1) ? deg[idx] : 0;
        s += vals[i];
    }
    int sc = s;
#pragma unroll
    for (int d = 1; d < 64; d <<= 1) {
        int t2 = __shfl_up(sc, d);
        if (lane >= d) sc += t2;
    }
    if (lane == 63) wsum[w] = sc;
    __syncthreads();
    int woff = 0;
    for (int i = 0; i < w; ++i) woff += wsum[i];
    int texcl = woff + sc - s;
    if (tid == 0) {
        int tot = 0;
        for (int i = 0; i < SCAN_BLOCK / 64; ++i) tot += wsum[i];
        bsums[blockIdx.x] = tot;
    }
    int run = 0;
#pragma unroll
    for (int i = 0; i < SCAN_ITEMS; ++i) {
        int idx = tbase + i;
        if (idx < n1) offs[idx] = texcl + run;
        run += vals[i];
    }
}

__global__ void scanB_kernel(int* __restrict__ bsums, int nb) {
    __shared__ int wsum[SCAN_BLOCK / 64];
    __shared__ int chunk_tot;
    int tid = threadIdx.x, lane = tid & 63, w = tid >> 6;
    int carry = 0;
    for (int base = 0; base < nb; base += SCAN_BLOCK) {
        int idx = base + tid;
        int v = (idx < nb) ? bsums[idx] : 0;
        int sc = v;
#pragma unroll
        for (int d = 1; d < 64; d <<= 1) {
            int t2 = __shfl_up(sc, d);
            if (lane >= d) sc += t2;
        }
        if (lane == 63) wsum[w] = sc;
        __syncthreads();
        int woff = 0;
        for (int i = 0; i < w; ++i) woff += wsum[i];
        if (idx < nb) bsums[idx] = carry + woff + sc - v;
        if (tid == SCAN_BLOCK - 1) chunk_tot = woff + sc;
        __syncthreads();
        carry += chunk_tot;
        __syncthreads();
    }
}

__global__ void scanC_kernel(int* __restrict__ offs, const int* __restrict__ bsums, int n1) {
    int t = blockIdx.x * blockDim.x + threadIdx.x;
    if (t < n1) offs[t] += bsums[t / SCAN_TILE];
}

// CSR fill + fused rbf, packed 4-byte record: (col << 15) | fp16(rbf) sans sign.
// NOTE (R5): bound by ~1M random dirty-line RMWs — record size does NOT matter;
// the fix (if needed) is destination binning, not packing.
__global__ void fill_kernel(const int* __restrict__ row, const int* __restrict__ col,
                            const float* __restrict__ pos, int* __restrict__ cursor,
                            unsigned* __restrict__ ecr, int e) {
    int t = blockIdx.x * blockDim.x + threadIdx.x;
    if (t >= e) return;
    int r = row[t], c = col[t];
    float dx = pos[3 * r]     - pos[3 * c];
    float dy = pos[3 * r + 1] - pos[3 * c + 1];
    float dz = pos[3 * r + 2] - pos[3 * c + 2];
    float rbf = expf(-sqrtf(dx * dx + dy * dy + dz * dz));
    unsigned short hb = __half_as_ushort(__float2half(rbf));   // sign bit = 0
    int p = atomicAdd(&cursor[r], 1);
    ecr[p] = ((unsigned)c << 15) | (unsigned)hb;
}

// y[n] = x[n] + sum_{(n,c)} bf16(x[c])*rbf — TWO nodes per wave.
// Consecutive nodes have CONTIGUOUS CSR ranges, so [offs[n0], offs[n0+2]) is one
// edge stream (avg 20 edges): the 8-wide unroll stays full, doubling row-loads
// in flight per wave vs 1-node (the R6 lesson: latency hiding needs chains AND
// occupancy — this adds chains at unchanged VGPR/wave count).
// Edge->node assignment is wave-uniform (idx < offs[n0+1]); branchless dual
// accumulate: acc0 += v*(cond?r:0), acc1 += v*(cond?0:r).
__global__ void gather_kernel(const float* __restrict__ x, const unsigned short* __restrict__ x16,
                              const int* __restrict__ offs, const unsigned* __restrict__ ecr,
                              float* __restrict__ y, int n) {
    int lane = threadIdx.x & 63;
    int wid = (blockIdx.x * blockDim.x + threadIdx.x) >> 6;
    int nw = (gridDim.x * blockDim.x) >> 6;
    int npair = (n + 1) >> 1;
    for (int p = wid; p < npair; p += nw) {
        int n0 = __builtin_amdgcn_readfirstlane(2 * p);
        bool two = (n0 + 1 < n);
        int beg = offs[n0];
        int b1  = offs[n0 + 1];
        int end = two ? offs[n0 + 2] : b1;
        float acc0 = x[(size_t)n0 * HID + lane];
        float acc1 = two ? x[((size_t)n0 + 1) * HID + lane] : 0.0f;
        for (int cb = beg; cb < end; cb += 64) {
            int m = end - cb; if (m > 64) m = 64;
            unsigned wrd = (lane < m) ? ecr[cb + lane] : 0u;
            int j = 0;
            for (; j + 8 <= m; j += 8) {
                unsigned w0 = __shfl(wrd, j);
                unsigned w1 = __shfl(wrd, j + 1);
                unsigned w2 = __shfl(wrd, j + 2);
                unsigned w3 = __shfl(wrd, j + 3);
                unsigned w4 = __shfl(wrd, j + 4);
                unsigned w5 = __shfl(wrd, j + 5);
                unsigned w6 = __shfl(wrd, j + 6);
                unsigned w7 = __shfl(wrd, j + 7);
                float v0 = bf16_bits_to_f32(x16[(w0 >> 15) * HID + lane]);
                float v1 = bf16_bits_to_f32(x16[(w1 >> 15) * HID + lane]);
                float v2 = bf16_bits_to_f32(x16[(w2 >> 15) * HID + lane]);
                float v3 = bf16_bits_to_f32(x16[(w3 >> 15) * HID + lane]);
                float v4 = bf16_bits_to_f32(x16[(w4 >> 15) * HID + lane]);
                float v5 = bf16_bits_to_f32(x16[(w5 >> 15) * HID + lane]);
                float v6 = bf16_bits_to_f32(x16[(w6 >> 15) * HID + lane]);
                float v7 = bf16_bits_to_f32(x16[(w7 >> 15) * HID + lane]);
#pragma unroll
                for (int i = 0; i < 8; ++i) {
                    unsigned wi = (i==0)?w0:(i==1)?w1:(i==2)?w2:(i==3)?w3:(i==4)?w4:(i==5)?w5:(i==6)?w6:w7;
                    float    vi = (i==0)?v0:(i==1)?v1:(i==2)?v2:(i==3)?v3:(i==4)?v4:(i==5)?v5:(i==6)?v6:v7;
                    bool c0 = (cb + j + i) < b1;          // wave-uniform
                    float r = rbf_of(wi);
                    acc0 = fmaf(vi, c0 ? r : 0.0f, acc0);
                    acc1 = fmaf(vi, c0 ? 0.0f : r, acc1);
                }
            }
            for (; j < m; ++j) {
                unsigned w0 = __shfl(wrd, j);
                float v0 = bf16_bits_to_f32(x16[(w0 >> 15) * HID + lane]);
                bool c0 = (cb + j) < b1;
                float r = rbf_of(w0);
                acc0 = fmaf(v0, c0 ? r : 0.0f, acc0);
                acc1 = fmaf(v0, c0 ? 0.0f : r, acc1);
            }
        }
        y[(size_t)n0 * HID + lane] = acc0;
        if (two) y[((size_t)n0 + 1) * HID + lane] = acc1;
    }
}

// out[n][h] = relu(b[h] + sum_k y[n][k] * W[h][k]); lane h holds W row h.
// FOUR nodes per iteration: 4 independent uniform-row scalar-load chains +
// 4 FMA chains (R5 had 2; the kernel is latency-bound on the row loads).
__global__ void linear_kernel(const float* __restrict__ x, const float* __restrict__ W,
                              const float* __restrict__ b, float* __restrict__ out,
                              unsigned short* __restrict__ out16, int n) {
    int h = threadIdx.x & 63;
    int wid = (blockIdx.x * blockDim.x + threadIdx.x) >> 6;
    int nw = (gridDim.x * blockDim.x) >> 6;
    float w[HID];
#pragma unroll
    for (int k = 0; k < HID; ++k) w[k] = W[h * HID + k];
    float bias = b[h];
    int nquad = (n + 3) >> 2;
    for (int q = wid; q < nquad; q += nw) {
        int n0 = __builtin_amdgcn_readfirstlane(4 * q);
        if (n0 + 3 < n) {
            const float* x0 = x + (size_t)n0 * HID;
            const float* x1 = x0 + HID;
            const float* x2 = x1 + HID;
            const float* x3 = x2 + HID;
            float a0 = bias, a1 = bias, a2 = bias, a3 = bias;
#pragma unroll
            for (int k = 0; k < HID; ++k) {
                a0 = fmaf(x0[k], w[k], a0);
                a1 = fmaf(x1[k], w[k], a1);
                a2 = fmaf(x2[k], w[k], a2);
                a3 = fmaf(x3[k], w[k], a3);
            }
            a0 = fmaxf(a0, 0.0f); a1 = fmaxf(a1, 0.0f);
            a2 = fmaxf(a2, 0.0f); a3 = fmaxf(a3, 0.0f);
            out[(size_t)n0 * HID + h] = a0;
            out[((size_t)n0 + 1) * HID + h] = a1;
            out[((size_t)n0 + 2) * HID + h] = a2;
            out[((size_t)n0 + 3) * HID + h] = a3;
            if (out16) {
                out16[(size_t)n0 * HID + h] = f32_to_bf16_bits(a0);
                out16[((size_t)n0 + 1) * HID + h] = f32_to_bf16_bits(a1);
                out16[((size_t)n0 + 2) * HID + h] = f32_to_bf16_bits(a2);
                out16[((size_t)n0 + 3) * HID + h] = f32_to_bf16_bits(a3);
            }
        } else {
            for (int nn = n0; nn < n; ++nn) {
                const float* xr = x + (size_t)nn * HID;
                float a = bias;
#pragma unroll
                for (int k = 0; k < HID; ++k) a = fmaf(xr[k], w[k], a);
                a = fmaxf(a, 0.0f);
                out[(size_t)nn * HID + h] = a;
                if (out16) out16[(size_t)nn * HID + h] = f32_to_bf16_bits(a);
            }
        }
    }
}

extern "C" void kernel_launch(void* const* d_in, const int* in_sizes, int n_in,
                              void* d_out, int out_size, void* d_ws, size_t ws_size,
                              hipStream_t stream) {
    const int*   z    = (const int*)d_in[0];
    const float* pos  = (const float*)d_in[1];
    const int*   eidx = (const int*)d_in[2];
    const float* emb  = (const float*)d_in[3];
    const float* Ws   = (const float*)d_in[4];
    const float* bs   = (const float*)d_in[5];
    int n = in_sizes[0];
    int e = in_sizes[2] / 2;
    int nlayers = in_sizes[4] / (HID * HID);
    const int* row = eidx;
    const int* col = eidx + e;
    float* out = (float*)d_out;

    char* ws = (char*)d_ws;
    float*          A      = (float*)ws;                                       // n*64 f32 (25.6 MB)
    unsigned short* A16    = (unsigned short*)(ws + (size_t)n * HID * 4);      // n*64 bf16 (12.8 MB)
    unsigned*       ecr    = (unsigned*)((char*)A16 + (size_t)n * HID * 2);    // e u32 (4 MB)
    int*            deg    = (int*)((char*)ecr + (size_t)e * 4);
    int*            offs   = deg + (n + 1);
    int*            cursor = offs + (n + 1);
    int*            bsums  = cursor + (n + 1);

    int n1 = n + 1;
    int nb = (n1 + SCAN_TILE - 1) / SCAN_TILE;

    hipMemsetAsync(deg, 0, n1 * sizeof(int), stream);
    embed_kernel<<<(n * HID + 255) / 256, 256, 0, stream>>>(z, emb, A, A16, n);
    hist_kernel<<<(e + 255) / 256, 256, 0, stream>>>(row, deg, e);
    scanA_kernel<<<nb, SCAN_BLOCK, 0, stream>>>(deg, offs, bsums, n1);
    scanB_kernel<<<1, SCAN_BLOCK, 0, stream>>>(bsums, nb);
    scanC_kernel<<<(n1 + 255) / 256, 256, 0, stream>>>(offs, bsums, n1);
    hipMemcpyAsync(cursor, offs, n * sizeof(int), hipMemcpyDeviceToDevice, stream);
    fill_kernel<<<(e + 255) / 256, 256, 0, stream>>>(row, col, pos, cursor, ecr, e);

    for (int l = 0; l < nlayers; ++l) {
        gather_kernel<<<2048, 256, 0, stream>>>(A, A16, offs, ecr, out, n);
        float* dst = (l == nlayers - 1) ? out : A;
        unsigned short* dst16 = (l == nlayers - 1) ? nullptr : A16;
        linear_kernel<<<1024, 256, 0, stream>>>(out, Ws + (size_t)l * HID * HID,
                                                bs + (size_t)l * HID, dst, dst16, n);
    }
}